// Round 3
// baseline (253.564 us; speedup 1.0000x reference)
//
#include <hip/hip_runtime.h>

typedef unsigned short u16;
typedef unsigned int   u32;
typedef unsigned long long u64;
typedef __bf16 bf16x8 __attribute__((ext_vector_type(8)));
typedef float  f32x4  __attribute__((ext_vector_type(4)));
typedef u32    u32x4  __attribute__((ext_vector_type(4)));
typedef u16    u16x4  __attribute__((ext_vector_type(4)));
typedef u16    u16x8v __attribute__((ext_vector_type(8)));

#define R_DIM 400
#define F_DIM 256
#define M_TOT 51200

__device__ __forceinline__ u16 f2bf(float f) {
    union { float f; u32 i; } x; x.f = f;
    u32 r = x.i + 0x7FFFu + ((x.i >> 16) & 1u);   // RNE
    return (u16)(r >> 16);
}

// ---------------------------------------------------------------------------
// Kernel 1: convert fp32 W -> bf16 B-fragments (unchanged, verified).
// Fragment g = (ks 0..7, T 0..15, L 0..63):
//   Wf[g][0..7] = bf16( W[T*16 + (L&15)][ks*32 + (L>>4)*8 .. +7] )
// ---------------------------------------------------------------------------
__global__ __launch_bounds__(256) void wprep_f32(const float* __restrict__ W,
                                                 u16* __restrict__ Wf) {
    int g  = blockIdx.x * 256 + threadIdx.x;   // 0..8191
    int ks = g >> 10;
    int T  = (g >> 6) & 15;
    int L  = g & 63;
    int n  = T * 16 + (L & 15);
    int k  = ks * 32 + (L >> 4) * 8;
    const float* wp = W + (size_t)n * F_DIM + k;
    float4 lo = *(const float4*)wp;
    float4 hi = *(const float4*)(wp + 4);
    u16x8v t;
    t[0] = f2bf(lo.x); t[1] = f2bf(lo.y); t[2] = f2bf(lo.z); t[3] = f2bf(lo.w);
    t[4] = f2bf(hi.x); t[5] = f2bf(hi.y); t[6] = f2bf(hi.z); t[7] = f2bf(hi.w);
    *(u16x8v*)(Wf + (size_t)g * 8) = t;
}

// ---------------------------------------------------------------------------
// Ballot-based ranks (verified): rank(c) = #{j: A[j]>A[c]} + #{j<c: A[j]==A[c]}.
// Wave-uniform counts via __ballot + popcount (scalar pipe).
// ---------------------------------------------------------------------------
__device__ __forceinline__ void compute_slots(float4 v0, float4 v1r, int lane,
                                              int diag, u32 es[7], u32* dup_out) {
    float4 v1 = v1r;
    if (lane >= 36) { v1.x = -1.f; v1.y = -1.f; v1.z = -1.f; v1.w = -1.f; } // A in [0,1): never counts
    float refs[6];
    refs[0] = __shfl(v0.x, 0);   // col 0
    refs[1] = __shfl(v0.x, 2);   // col 8
    refs[2] = __shfl(v0.y, 2);   // col 9
    refs[3] = __shfl(v0.z, 2);   // col 10
    refs[4] = __shfl(v0.w, 2);   // col 11
    refs[5] = __shfl(v0.x, 3);   // col 12
    const int cols[6] = {0, 8, 9, 10, 11, 12};
    float e0[4] = {v0.x, v0.y, v0.z, v0.w};
    float e1[4] = {v1.x, v1.y, v1.z, v1.w};
    u32 cnt[6];
#pragma unroll
    for (int k = 0; k < 6; k++) {
        int c = 0;
#pragma unroll
        for (int jj = 0; jj < 4; jj++) {
            int j = (lane << 2) + jj;
            c += __popcll(__ballot(e0[jj] > refs[k] ||
                                   (e0[jj] == refs[k] && j < cols[k])));
            c += __popcll(__ballot(e1[jj] > refs[k]));   // j>=256 > cols[k] always
        }
        cnt[k] = (u32)c;
    }
    bool dup = (diag == (int)cnt[0]) | (diag == (int)cnt[1]) | (diag == (int)cnt[2]) |
               (diag == (int)cnt[3]) | (diag == (int)cnt[4]) | (diag == (int)cnt[5]);
#pragma unroll
    for (int s = 0; s < 6; s++) es[s] = cnt[s];
    es[6] = (u32)diag;
    *dup_out = dup ? 1u : 0u;
}

// ---------------------------------------------------------------------------
// Kernel 2: 1-WAVE BLOCKS, barrier-free, deep-pipelined.
// Each wave owns a full 16-row m-tile: 3-buffer 2-deep pipeline
// {issue A rr+2 | slots rr | issue gather rr | consume rr-2} -> bf16 LDS tile
// -> probe-decoded MFMA K-loop over all 16 n-tiles -> relu/bias/residual.
// No __syncthreads: all LDS deps are within-wave (compiler lgkmcnt).
// ---------------------------------------------------------------------------
__global__ __launch_bounds__(64, 3) void gcn_fused(const float* __restrict__ A,
                                                   const float* __restrict__ feats,
                                                   const u16*  __restrict__ Wf,
                                                   const float* __restrict__ bias,
                                                   float* __restrict__ out) {
    __shared__ __align__(16) u16 agg_lds[16][264];   // bf16 agg tile (8.25 KB)
    __shared__ __align__(16) u16 probeA[16][32];
    __shared__ __align__(16) u16 probeB[16][32];

    const int lane = threadIdx.x & 63;
    // XCD swizzle: XCD x (= bid&7) owns contiguous rows [x*6400, (x+1)*6400)
    const int bid = (int)blockIdx.x;
    const int m0  = ((bid & 7) * 400 + (bid >> 3)) * 16;
    const int kg  = (lane >> 4) << 3;
    const int bh  = m0 / R_DIM;          // 16 | 400 -> block never spans bh
    const int i0  = m0 - bh * R_DIM;     // diag index of row 0

    // probe tiles: A[m][0]=m, A[m][1]=1; B[n][0]=16, B[n][1]=n  -> D=16m+n
    for (int e = lane; e < 512; e += 64) {
        int r = e >> 5, k = e & 31;
        probeA[r][k] = (k == 0) ? f2bf((float)r) : ((k == 1) ? f2bf(1.0f) : (u16)0);
        probeB[r][k] = (k == 0) ? f2bf(16.0f)    : ((k == 1) ? f2bf((float)r) : (u16)0);
    }

    const float* Ab = A + (size_t)m0 * R_DIM;
    const float* fb = feats + (size_t)bh * R_DIM * F_DIM + lane * 4;

    // ---- 3-buffer, 2-deep pipelined rank+gather over 16 rows ----
    {
        float4 a0b[3], a1b[3];
        float  wb[3][7];
        float4 fbv[3][7];
        u32    dupb[3];

        // prologue: issue A-row loads for rr = 0, 1
#pragma unroll
        for (int p = 0; p < 2; p++) {
            const float* Ar = Ab + (size_t)p * R_DIM;
            a0b[p] = *(const float4*)(Ar + lane * 4);
            a1b[p] = *(const float4*)(Ar + (lane < 36 ? 256 + lane * 4 : 0));
        }

#pragma unroll
        for (int rr = 0; rr < 16; rr++) {
            if (rr + 2 < 16) {                       // 2-deep A prefetch
                const float* An = Ab + (size_t)(rr + 2) * R_DIM;
                a0b[(rr + 2) % 3] = *(const float4*)(An + lane * 4);
                a1b[(rr + 2) % 3] = *(const float4*)(An + (lane < 36 ? 256 + lane * 4 : 0));
            }

            u32 es[7], dupm;
            compute_slots(a0b[rr % 3], a1b[rr % 3], lane, i0 + rr, es, &dupm);
            dupb[rr % 3] = dupm;

            const float* Ar = Ab + (size_t)rr * R_DIM;
#pragma unroll
            for (int s = 0; s < 7; s++) {            // issue gather rr
                u32 e = es[s];
                wb[rr % 3][s]  = Ar[e];
                fbv[rr % 3][s] = *(const float4*)(fb + (size_t)e * F_DIM);
            }

            if (rr >= 2) {                           // consume rr-2 (2-deep cover)
                const int rc = rr - 2, bi = rc % 3;
                float a0 = 0.f, a1 = 0.f, a2 = 0.f, a3 = 0.f;
#pragma unroll
                for (int s = 0; s < 7; s++) {
                    float ws = (s == 6 && dupb[bi]) ? 0.f : wb[bi][s];
                    a0 += ws * fbv[bi][s].x; a1 += ws * fbv[bi][s].y;
                    a2 += ws * fbv[bi][s].z; a3 += ws * fbv[bi][s].w;
                }
                u16x4 st = { f2bf(a0), f2bf(a1), f2bf(a2), f2bf(a3) };
                *(u16x4*)&agg_lds[rc][lane * 4] = st;
            }
        }
        // drain rows 14, 15
#pragma unroll
        for (int rc = 14; rc < 16; rc++) {
            const int bi = rc % 3;
            float a0 = 0.f, a1 = 0.f, a2 = 0.f, a3 = 0.f;
#pragma unroll
            for (int s = 0; s < 7; s++) {
                float ws = (s == 6 && dupb[bi]) ? 0.f : wb[bi][s];
                a0 += ws * fbv[bi][s].x; a1 += ws * fbv[bi][s].y;
                a2 += ws * fbv[bi][s].z; a3 += ws * fbv[bi][s].w;
            }
            u16x4 st = { f2bf(a0), f2bf(a1), f2bf(a2), f2bf(a3) };
            *(u16x4*)&agg_lds[rc][lane * 4] = st;
        }
    }

    // ---- probe MFMA: decode true per-register (row,col) ----
    int rowi[4], coli[4];
    {
        bf16x8 pa = *(const bf16x8*)&probeA[lane & 15][kg];
        bf16x8 pb = *(const bf16x8*)&probeB[lane & 15][kg];
        f32x4 pd = {0.f, 0.f, 0.f, 0.f};
        pd = __builtin_amdgcn_mfma_f32_16x16x32_bf16(pa, pb, pd, 0, 0, 0);
#pragma unroll
        for (int reg = 0; reg < 4; reg++) {
            int v = (int)(pd[reg] + 0.5f);
            rowi[reg] = v >> 4;
            coli[reg] = v & 15;
        }
    }

    // ---- MFMA K-loop: 1 m-tile x 16 n-tiles (Wf direct from global, L2-hot) ----
    f32x4 acc[16];
#pragma unroll
    for (int nt = 0; nt < 16; nt++) acc[nt] = (f32x4){0.f, 0.f, 0.f, 0.f};

#pragma unroll
    for (int ks = 0; ks < 8; ks++) {
        bf16x8 af = *(const bf16x8*)&agg_lds[lane & 15][ks * 32 + kg];
#pragma unroll
        for (int nt = 0; nt < 16; nt++) {
            u32x4 v = *(const u32x4*)(Wf + ((size_t)(ks * 16 + nt) * 64 + lane) * 8);
            bf16x8 b = __builtin_bit_cast(bf16x8, v);
            acc[nt] = __builtin_amdgcn_mfma_f32_16x16x32_bf16(af, b, acc[nt], 0, 0, 0);
        }
    }

    // ---- epilogue: relu(acc + b) + feats -> out (fp32) ----
#pragma unroll
    for (int nt = 0; nt < 16; nt++) {
        int nb = nt * 16;
#pragma unroll
        for (int reg = 0; reg < 4; reg++) {
            int gn = nb + coli[reg];
            float bn = bias[gn];
            int gm = m0 + rowi[reg];
            size_t off = (size_t)gm * F_DIM + gn;
            out[off] = fmaxf(acc[nt][reg] + bn, 0.f) + feats[off];
        }
    }
}

extern "C" void kernel_launch(void* const* d_in, const int* in_sizes, int n_in,
                              void* d_out, int out_size, void* d_ws, size_t ws_size,
                              hipStream_t stream) {
    const float* A     = (const float*)d_in[0];   // [16,8,400,400] fp32
    const float* feats = (const float*)d_in[1];   // [16,8,400,256] fp32
    const float* W     = (const float*)d_in[2];   // [256,256] fp32
    const float* bias  = (const float*)d_in[3];   // [256] fp32
    float* out = (float*)d_out;                   // [16,8,400,256] fp32

    u16* Wf = (u16*)d_ws;                         // 128 KB

    wprep_f32<<<32, 256, 0, stream>>>(W, Wf);
    gcn_fused<<<M_TOT / 16, 64, 0, stream>>>(A, feats, Wf, bias, out);
}

// Round 5
// 231.411 us; speedup vs baseline: 1.0957x; 1.0957x over previous
//
#include <hip/hip_runtime.h>

typedef unsigned short u16;
typedef unsigned int   u32;
typedef unsigned long long u64;
typedef __bf16 bf16x8 __attribute__((ext_vector_type(8)));
typedef float  f32x4  __attribute__((ext_vector_type(4)));
typedef u32    u32x4  __attribute__((ext_vector_type(4)));
typedef u16    u16x4  __attribute__((ext_vector_type(4)));
typedef u16    u16x8v __attribute__((ext_vector_type(8)));

#define R_DIM 400
#define F_DIM 256
#define M_TOT 51200

// counted waitcnt (never 0 in-loop) + scheduler fence (guide rule #18)
#define VMWAIT(n) do { \
    asm volatile("s_waitcnt vmcnt(" #n ")" ::: "memory"); \
    __builtin_amdgcn_sched_barrier(0); \
} while (0)

typedef const __attribute__((address_space(1))) void* gvp;
typedef __attribute__((address_space(3)))       void* lvp;

__device__ __forceinline__ u16 f2bf(float f) {
    union { float f; u32 i; } x; x.f = f;
    u32 r = x.i + 0x7FFFu + ((x.i >> 16) & 1u);   // RNE
    return (u16)(r >> 16);
}

// ---------------------------------------------------------------------------
// Kernel 1: convert fp32 W -> bf16 B-fragments (unchanged, verified).
// ---------------------------------------------------------------------------
__global__ __launch_bounds__(256) void wprep_f32(const float* __restrict__ W,
                                                 u16* __restrict__ Wf) {
    int g  = blockIdx.x * 256 + threadIdx.x;   // 0..8191
    int ks = g >> 10;
    int T  = (g >> 6) & 15;
    int L  = g & 63;
    int n  = T * 16 + (L & 15);
    int k  = ks * 32 + (L >> 4) * 8;
    const float* wp = W + (size_t)n * F_DIM + k;
    float4 lo = *(const float4*)wp;
    float4 hi = *(const float4*)(wp + 4);
    u16x8v t;
    t[0] = f2bf(lo.x); t[1] = f2bf(lo.y); t[2] = f2bf(lo.z); t[3] = f2bf(lo.w);
    t[4] = f2bf(hi.x); t[5] = f2bf(hi.y); t[6] = f2bf(hi.z); t[7] = f2bf(hi.w);
    *(u16x8v*)(Wf + (size_t)g * 8) = t;
}

// ---------------------------------------------------------------------------
// Ballot-based ranks (verified): rank(c) = #{j: A[j]>A[c]} + #{j<c: A[j]==A[c]}.
// ---------------------------------------------------------------------------
__device__ __forceinline__ void compute_slots(float4 v0, float4 v1r, int lane,
                                              int diag, u32 es[7], u32* dup_out) {
    float4 v1 = v1r;
    if (lane >= 36) { v1.x = -1.f; v1.y = -1.f; v1.z = -1.f; v1.w = -1.f; } // A in [0,1)
    float refs[6];
    refs[0] = __shfl(v0.x, 0);   // col 0
    refs[1] = __shfl(v0.x, 2);   // col 8
    refs[2] = __shfl(v0.y, 2);   // col 9
    refs[3] = __shfl(v0.z, 2);   // col 10
    refs[4] = __shfl(v0.w, 2);   // col 11
    refs[5] = __shfl(v0.x, 3);   // col 12
    const int cols[6] = {0, 8, 9, 10, 11, 12};
    float e0[4] = {v0.x, v0.y, v0.z, v0.w};
    float e1[4] = {v1.x, v1.y, v1.z, v1.w};
    u32 cnt[6];
#pragma unroll
    for (int k = 0; k < 6; k++) {
        int c = 0;
#pragma unroll
        for (int jj = 0; jj < 4; jj++) {
            int j = (lane << 2) + jj;
            c += __popcll(__ballot(e0[jj] > refs[k] ||
                                   (e0[jj] == refs[k] && j < cols[k])));
            c += __popcll(__ballot(e1[jj] > refs[k]));   // j>=256 > cols[k] always
        }
        cnt[k] = (u32)c;
    }
    bool dup = (diag == (int)cnt[0]) | (diag == (int)cnt[1]) | (diag == (int)cnt[2]) |
               (diag == (int)cnt[3]) | (diag == (int)cnt[4]) | (diag == (int)cnt[5]);
#pragma unroll
    for (int s = 0; s < 6; s++) es[s] = cnt[s];
    es[6] = (u32)diag;
    *dup_out = dup ? 1u : 0u;
}

// ---------------------------------------------------------------------------
// Kernel 2: R2 shell + DMA gather (global_load_lds) + counted vmcnt pipeline.
// 32 rows/block, 256 threads, 1600 blocks, XCD-contiguous swizzle.
// Per wave (8 rows): {prefetch A rr+2 (reg ring) | ballots rr | w-loads rr |
//   7x global_load_lds rr -> stage[wid][rr&1] | vmcnt(9/7) | consume rr-1}.
// DMA loads cannot be sunk by the compiler -> forced ~7-16KB in flight/wave.
// vmcnt accounting: at consume of rr-1, >=9 (rr<6) / >=7 (rr>=6) VMEM ops are
// guaranteed issued after that row's DMA group (7 DMA + 2 A-prefetch), so
// vmcnt(9)/vmcnt(7) is exact-or-conservative regardless of w-load codegen.
// ---------------------------------------------------------------------------
__global__ __launch_bounds__(256) void gcn_fused(const float* __restrict__ A,
                                                 const float* __restrict__ feats,
                                                 const u16*  __restrict__ Wf,
                                                 const float* __restrict__ bias,
                                                 float* __restrict__ out) {
    __shared__ __align__(16) u16   agg_lds[32][264];       // 16.9 KB
    __shared__ __align__(16) float stage[4][2][7][256];    // 56 KB DMA ring
    __shared__ __align__(16) u16   probeA[16][32];
    __shared__ __align__(16) u16   probeB[16][32];

    const int tid = threadIdx.x, wid = tid >> 6, lane = tid & 63;
    const int bid = (int)blockIdx.x;
    const int m0  = ((bid & 7) * 200 + (bid >> 3)) * 32;
    const int kg  = (lane >> 4) << 3;

    // probe tiles: A[m][0]=m, A[m][1]=1; B[n][0]=16, B[n][1]=n  -> D=16m+n
    for (int e = tid; e < 512; e += 256) {
        int r = e >> 5, k = e & 31;
        probeA[r][k] = (k == 0) ? f2bf((float)r) : ((k == 1) ? f2bf(1.0f) : (u16)0);
        probeB[r][k] = (k == 0) ? f2bf(16.0f)    : ((k == 1) ? f2bf((float)r) : (u16)0);
    }

    const int rbase = wid * 8;   // this wave's rows: rbase..rbase+7

    // ---- DMA-pipelined rank+gather over 8 rows ----
    {
        float4 a0b[3], a1b[3];          // A-row register ring (pinned by asm fences)
        float  wb[2][7];
        u32    dupb[2];

        // prologue: A-row loads for rr = 0, 1
#pragma unroll
        for (int p = 0; p < 2; p++) {
            const float* Ar = A + (size_t)(m0 + rbase + p) * R_DIM;
            a0b[p] = *(const float4*)(Ar + lane * 4);
            a1b[p] = *(const float4*)(Ar + (lane < 36 ? 256 + lane * 4 : 0));
        }

#pragma unroll
        for (int rr = 0; rr < 8; rr++) {
            const int r   = rbase + rr;
            const int row = m0 + r;
            const int bh  = row / R_DIM;
            const int dia = row - bh * R_DIM;

            if (rr + 2 < 8) {                        // 2-deep A prefetch (fenced)
                const float* An = A + (size_t)(row + 2) * R_DIM;
                a0b[(rr + 2) % 3] = *(const float4*)(An + lane * 4);
                a1b[(rr + 2) % 3] = *(const float4*)(An + (lane < 36 ? 256 + lane * 4 : 0));
            }

            u32 es[7], dupm;
            compute_slots(a0b[rr % 3], a1b[rr % 3], lane, dia, es, &dupm);
            dupb[rr & 1] = dupm;

            const float* Ar = A + (size_t)row * R_DIM;
            const float* fb = feats + (size_t)bh * R_DIM * F_DIM + lane * 4;
#pragma unroll
            for (int s = 0; s < 7; s++) wb[rr & 1][s] = Ar[es[s]];   // L1-hot scalars
#pragma unroll
            for (int s = 0; s < 7; s++)                              // 7x 1KB DMA
                __builtin_amdgcn_global_load_lds(
                    (gvp)(fb + (size_t)es[s] * F_DIM),
                    (lvp)&stage[wid][rr & 1][s][0], 16, 0, 0);

            if (rr >= 1) {                           // consume rr-1
                if (rr < 6) { VMWAIT(9); } else { VMWAIT(7); }
                const int bi = (rr - 1) & 1;
                const float* sb = &stage[wid][bi][0][lane * 4];
                float a0 = 0.f, a1 = 0.f, a2 = 0.f, a3 = 0.f;
#pragma unroll
                for (int s = 0; s < 7; s++) {
                    float4 f = *(const float4*)(sb + s * 256);
                    float ws = (s == 6 && dupb[bi]) ? 0.f : wb[bi][s];
                    a0 += ws * f.x; a1 += ws * f.y; a2 += ws * f.z; a3 += ws * f.w;
                }
                u16x4 st = { f2bf(a0), f2bf(a1), f2bf(a2), f2bf(a3) };
                *(u16x4*)&agg_lds[r - 1][lane * 4] = st;
            }
        }
        // drain: consume rr = 7
        {
            VMWAIT(0);
            const int bi = 7 & 1;
            const float* sb = &stage[wid][bi][0][lane * 4];
            float a0 = 0.f, a1 = 0.f, a2 = 0.f, a3 = 0.f;
#pragma unroll
            for (int s = 0; s < 7; s++) {
                float4 f = *(const float4*)(sb + s * 256);
                float ws = (s == 6 && dupb[bi]) ? 0.f : wb[bi][s];
                a0 += ws * f.x; a1 += ws * f.y; a2 += ws * f.z; a3 += ws * f.w;
            }
            u16x4 st = { f2bf(a0), f2bf(a1), f2bf(a2), f2bf(a3) };
            *(u16x4*)&agg_lds[rbase + 7][lane * 4] = st;
        }
    }
    __syncthreads();

    // ---- probe MFMA: decode true per-register (row,col) ----
    int rowi[4], coli[4];
    {
        bf16x8 pa = *(const bf16x8*)&probeA[lane & 15][kg];
        bf16x8 pb = *(const bf16x8*)&probeB[lane & 15][kg];
        f32x4 pd = {0.f, 0.f, 0.f, 0.f};
        pd = __builtin_amdgcn_mfma_f32_16x16x32_bf16(pa, pb, pd, 0, 0, 0);
#pragma unroll
        for (int reg = 0; reg < 4; reg++) {
            int v = (int)(pd[reg] + 0.5f);
            rowi[reg] = v >> 4;
            coli[reg] = v & 15;
        }
    }

    // ---- MFMA K-loop (verified R2 structure) ----
    f32x4 acc[2][4];
#pragma unroll
    for (int mt = 0; mt < 2; mt++)
#pragma unroll
        for (int nt = 0; nt < 4; nt++)
            acc[mt][nt] = (f32x4){0.f, 0.f, 0.f, 0.f};

#pragma unroll
    for (int ks = 0; ks < 8; ks++) {
        bf16x8 af[2], bfr[4];
#pragma unroll
        for (int mt = 0; mt < 2; mt++)
            af[mt] = *(const bf16x8*)&agg_lds[mt * 16 + (lane & 15)][ks * 32 + kg];
#pragma unroll
        for (int nt = 0; nt < 4; nt++) {
            int T = wid * 4 + nt;             // wave w owns n-tiles 4w..4w+3
            u32x4 v = *(const u32x4*)(Wf + ((size_t)(ks * 16 + T) * 64 + lane) * 8);
            bfr[nt] = __builtin_bit_cast(bf16x8, v);
        }
#pragma unroll
        for (int mt = 0; mt < 2; mt++)
#pragma unroll
            for (int nt = 0; nt < 4; nt++)
                acc[mt][nt] = __builtin_amdgcn_mfma_f32_16x16x32_bf16(
                    af[mt], bfr[nt], acc[mt][nt], 0, 0, 0);
    }

    // ---- epilogue: relu(acc + b) + feats -> out (fp32) ----
#pragma unroll
    for (int nt = 0; nt < 4; nt++) {
        int nb = wid * 64 + nt * 16;
#pragma unroll
        for (int reg = 0; reg < 4; reg++) {
            int gn = nb + coli[reg];
            float bn = bias[gn];
#pragma unroll
            for (int mt = 0; mt < 2; mt++) {
                int gm = m0 + mt * 16 + rowi[reg];
                size_t off = (size_t)gm * F_DIM + gn;
                out[off] = fmaxf(acc[mt][nt][reg] + bn, 0.f) + feats[off];
            }
        }
    }
}

extern "C" void kernel_launch(void* const* d_in, const int* in_sizes, int n_in,
                              void* d_out, int out_size, void* d_ws, size_t ws_size,
                              hipStream_t stream) {
    const float* A     = (const float*)d_in[0];   // [16,8,400,400] fp32
    const float* feats = (const float*)d_in[1];   // [16,8,400,256] fp32
    const float* W     = (const float*)d_in[2];   // [256,256] fp32
    const float* bias  = (const float*)d_in[3];   // [256] fp32
    float* out = (float*)d_out;                   // [16,8,400,256] fp32

    u16* Wf = (u16*)d_ws;                         // 128 KB

    wprep_f32<<<32, 256, 0, stream>>>(W, Wf);
    gcn_fused<<<M_TOT / 32, 256, 0, stream>>>(A, feats, Wf, bias, out);
}

// Round 6
// 211.742 us; speedup vs baseline: 1.1975x; 1.0929x over previous
//
#include <hip/hip_runtime.h>

typedef unsigned short u16;
typedef unsigned int   u32;
typedef unsigned long long u64;
typedef __bf16 bf16x8 __attribute__((ext_vector_type(8)));
typedef float  f32x4  __attribute__((ext_vector_type(4)));
typedef u32    u32x4  __attribute__((ext_vector_type(4)));
typedef u16    u16x4  __attribute__((ext_vector_type(4)));
typedef u16    u16x8v __attribute__((ext_vector_type(8)));

#define R_DIM 400
#define F_DIM 256
#define M_TOT 51200

__device__ __forceinline__ u16 f2bf(float f) {
    union { float f; u32 i; } x; x.f = f;
    u32 r = x.i + 0x7FFFu + ((x.i >> 16) & 1u);   // RNE
    return (u16)(r >> 16);
}

// ---------------------------------------------------------------------------
// Kernel 1: convert fp32 W -> bf16 B-fragments (unchanged, verified).
// Fragment g = (ks 0..7, T 0..15, L 0..63):
//   Wf[g][0..7] = bf16( W[T*16 + (L&15)][ks*32 + (L>>4)*8 .. +7] )
// ---------------------------------------------------------------------------
__global__ __launch_bounds__(256) void wprep_f32(const float* __restrict__ W,
                                                 u16* __restrict__ Wf) {
    int g  = blockIdx.x * 256 + threadIdx.x;   // 0..8191
    int ks = g >> 10;
    int T  = (g >> 6) & 15;
    int L  = g & 63;
    int n  = T * 16 + (L & 15);
    int k  = ks * 32 + (L >> 4) * 8;
    const float* wp = W + (size_t)n * F_DIM + k;
    float4 lo = *(const float4*)wp;
    float4 hi = *(const float4*)(wp + 4);
    u16x8v t;
    t[0] = f2bf(lo.x); t[1] = f2bf(lo.y); t[2] = f2bf(lo.z); t[3] = f2bf(lo.w);
    t[4] = f2bf(hi.x); t[5] = f2bf(hi.y); t[6] = f2bf(hi.z); t[7] = f2bf(hi.w);
    *(u16x8v*)(Wf + (size_t)g * 8) = t;
}

// ---------------------------------------------------------------------------
// Ballot-based ranks (verified): rank(c) = #{j: A[j]>A[c]} + #{j<c: A[j]==A[c]}.
// Wave-uniform counts via __ballot + popcount (scalar pipe).
// ---------------------------------------------------------------------------
__device__ __forceinline__ void compute_slots(float4 v0, float4 v1r, int lane,
                                              int diag, u32 es[7], u32* dup_out) {
    float4 v1 = v1r;
    if (lane >= 36) { v1.x = -1.f; v1.y = -1.f; v1.z = -1.f; v1.w = -1.f; } // A in [0,1)
    float refs[6];
    refs[0] = __shfl(v0.x, 0);   // col 0
    refs[1] = __shfl(v0.x, 2);   // col 8
    refs[2] = __shfl(v0.y, 2);   // col 9
    refs[3] = __shfl(v0.z, 2);   // col 10
    refs[4] = __shfl(v0.w, 2);   // col 11
    refs[5] = __shfl(v0.x, 3);   // col 12
    const int cols[6] = {0, 8, 9, 10, 11, 12};
    float e0[4] = {v0.x, v0.y, v0.z, v0.w};
    float e1[4] = {v1.x, v1.y, v1.z, v1.w};
    u32 cnt[6];
#pragma unroll
    for (int k = 0; k < 6; k++) {
        int c = 0;
#pragma unroll
        for (int jj = 0; jj < 4; jj++) {
            int j = (lane << 2) + jj;
            c += __popcll(__ballot(e0[jj] > refs[k] ||
                                   (e0[jj] == refs[k] && j < cols[k])));
            c += __popcll(__ballot(e1[jj] > refs[k]));   // j>=256 > cols[k] always
        }
        cnt[k] = (u32)c;
    }
    bool dup = (diag == (int)cnt[0]) | (diag == (int)cnt[1]) | (diag == (int)cnt[2]) |
               (diag == (int)cnt[3]) | (diag == (int)cnt[4]) | (diag == (int)cnt[5]);
#pragma unroll
    for (int s = 0; s < 6; s++) es[s] = cnt[s];
    es[6] = (u32)diag;
    *dup_out = dup ? 1u : 0u;
}

// ---------------------------------------------------------------------------
// Kernel 2: GATHER — 1 row per wave, no LDS, no barriers, max TLP.
// 12800 blocks x 256 threads (4 independent waves/block).
// XCD swizzle: XCD x owns contiguous rows [x*6400, (x+1)*6400) -> feats
// gather stays within ~16 bh groups per XCD (L2/L3-local).
// Writes agg[row][0..255] bf16 (coalesced 512B per wave) — identical bits
// to the fused kernel's agg_lds values (same ballots, order, f2bf).
// ---------------------------------------------------------------------------
__global__ __launch_bounds__(256, 4) void gcn_gather(const float* __restrict__ A,
                                                     const float* __restrict__ feats,
                                                     u16* __restrict__ agg) {
    const int tid = threadIdx.x, wid = tid >> 6, lane = tid & 63;
    const int bid = (int)blockIdx.x;
    const int row = ((bid & 7) * 1600 + (bid >> 3)) * 4 + wid;
    const int bh  = row / R_DIM;
    const int dia = row - bh * R_DIM;

    const float* Ar = A + (size_t)row * R_DIM;
    float4 v0 = *(const float4*)(Ar + lane * 4);
    float4 v1 = *(const float4*)(Ar + (lane < 36 ? 256 + lane * 4 : 0));

    u32 es[7], dupm;
    compute_slots(v0, v1, lane, dia, es, &dupm);

    const float* fb = feats + (size_t)bh * R_DIM * F_DIM + lane * 4;
    float w[7]; float4 f[7];
#pragma unroll
    for (int s = 0; s < 7; s++) {
        u32 e = es[s];
        w[s] = Ar[e];                                    // L1-hot (row just read)
        f[s] = *(const float4*)(fb + (size_t)e * F_DIM); // coalesced 1KB
    }
    float a0 = 0.f, a1 = 0.f, a2 = 0.f, a3 = 0.f;
#pragma unroll
    for (int s = 0; s < 7; s++) {
        float ws = (s == 6 && dupm) ? 0.f : w[s];
        a0 += ws * f[s].x; a1 += ws * f[s].y; a2 += ws * f[s].z; a3 += ws * f[s].w;
    }
    u16x4 st = { f2bf(a0), f2bf(a1), f2bf(a2), f2bf(a3) };
    *(u16x4*)(agg + (size_t)row * F_DIM + lane * 4) = st;
}

// ---------------------------------------------------------------------------
// Kernel 3: GEMM — 32 rows/block, 1600 blocks, no agg LDS, no gather coupling.
// Wave w: m-tile (w&1), n-tiles (w>>1)*8 .. +7; acc[8].
// A-fragments per-lane direct from global agg (same XCD swizzle as gather ->
// each XCD's 3.3MB agg span is L2-resident). Wf fragments as verified.
// Probe-decoded C/D layout + relu/bias/residual epilogue (verified).
// ---------------------------------------------------------------------------
__global__ __launch_bounds__(256, 4) void gcn_gemm(const u16*  __restrict__ agg,
                                                   const u16*  __restrict__ Wf,
                                                   const float* __restrict__ bias,
                                                   const float* __restrict__ feats,
                                                   float* __restrict__ out) {
    __shared__ __align__(16) u16 probeA[16][32];
    __shared__ __align__(16) u16 probeB[16][32];

    const int tid = threadIdx.x, wid = tid >> 6, lane = tid & 63;
    const int bid = (int)blockIdx.x;
    const int m0  = ((bid & 7) * 200 + (bid >> 3)) * 32;
    const int kg  = (lane >> 4) << 3;
    const int mt  = wid & 1;         // m-tile within block
    const int nh  = wid >> 1;        // n-half: n-tiles nh*8 .. nh*8+7

    // probe tiles: A[m][0]=m, A[m][1]=1; B[n][0]=16, B[n][1]=n  -> D=16m+n
    for (int e = tid; e < 512; e += 256) {
        int r = e >> 5, k = e & 31;
        probeA[r][k] = (k == 0) ? f2bf((float)r) : ((k == 1) ? f2bf(1.0f) : (u16)0);
        probeB[r][k] = (k == 0) ? f2bf(16.0f)    : ((k == 1) ? f2bf((float)r) : (u16)0);
    }
    __syncthreads();

    // ---- probe MFMA: decode true per-register (row,col) ----
    int rowi[4], coli[4];
    {
        bf16x8 pa = *(const bf16x8*)&probeA[lane & 15][kg];
        bf16x8 pb = *(const bf16x8*)&probeB[lane & 15][kg];
        f32x4 pd = {0.f, 0.f, 0.f, 0.f};
        pd = __builtin_amdgcn_mfma_f32_16x16x32_bf16(pa, pb, pd, 0, 0, 0);
#pragma unroll
        for (int reg = 0; reg < 4; reg++) {
            int v = (int)(pd[reg] + 0.5f);
            rowi[reg] = v >> 4;
            coli[reg] = v & 15;
        }
    }

    // ---- MFMA K-loop: af per-lane direct from global agg ----
    f32x4 acc[8];
#pragma unroll
    for (int nt = 0; nt < 8; nt++) acc[nt] = (f32x4){0.f, 0.f, 0.f, 0.f};

    const u16* ab = agg + (size_t)(m0 + mt * 16 + (lane & 15)) * F_DIM + kg;
#pragma unroll
    for (int ks = 0; ks < 8; ks++) {
        bf16x8 af = *(const bf16x8*)(ab + ks * 32);
#pragma unroll
        for (int nt = 0; nt < 8; nt++) {
            int T = nh * 8 + nt;
            u32x4 v = *(const u32x4*)(Wf + ((size_t)(ks * 16 + T) * 64 + lane) * 8);
            bf16x8 b = __builtin_bit_cast(bf16x8, v);
            acc[nt] = __builtin_amdgcn_mfma_f32_16x16x32_bf16(af, b, acc[nt], 0, 0, 0);
        }
    }

    // ---- epilogue: relu(acc + b) + feats -> out (fp32) ----
#pragma unroll
    for (int nt = 0; nt < 8; nt++) {
        int nb = (nh * 8 + nt) * 16;
#pragma unroll
        for (int reg = 0; reg < 4; reg++) {
            int gn = nb + coli[reg];
            float bn = bias[gn];
            int gm = m0 + mt * 16 + rowi[reg];
            size_t off = (size_t)gm * F_DIM + gn;
            out[off] = fmaxf(acc[nt][reg] + bn, 0.f) + feats[off];
        }
    }
}

extern "C" void kernel_launch(void* const* d_in, const int* in_sizes, int n_in,
                              void* d_out, int out_size, void* d_ws, size_t ws_size,
                              hipStream_t stream) {
    const float* A     = (const float*)d_in[0];   // [16,8,400,400] fp32
    const float* feats = (const float*)d_in[1];   // [16,8,400,256] fp32
    const float* W     = (const float*)d_in[2];   // [256,256] fp32
    const float* bias  = (const float*)d_in[3];   // [256] fp32
    float* out = (float*)d_out;                   // [16,8,400,256] fp32

    u16* Wf  = (u16*)d_ws;                                  // 128 KB
    u16* agg = (u16*)((char*)d_ws + (size_t)128 * 1024);    // 26.2 MB bf16 agg

    wprep_f32 <<<32,    256, 0, stream>>>(W, Wf);
    gcn_gather<<<12800, 256, 0, stream>>>(A, feats, agg);
    gcn_gemm  <<<1600,  256, 0, stream>>>(agg, Wf, bias, feats, out);
}